// Round 4
// baseline (136.404 us; speedup 1.0000x reference)
//
#include <hip/hip_runtime.h>
#include <math.h>

#define HWSZ 1024
#define HH 32
#define WW 32
#define C 256
#define CK 32
#define CV 128
#define T 3
#define WSZ 15
#define PADSZ 7
#define PADDED 46
#define PP (PADDED*PADDED)   // 2116
#define KK (T*WSZ*WSZ)       // 675
#define B 2
#define NOUT 160             // CK + CV
#define KC 32                // k-chunk
#define PIXT 32              // pixel tile (one image row)

// workspace layout (floats)
static const size_t OFF_QK   = 0;                          // B*HWSZ*CK        = 65536   ([pix][32])
static const size_t OFF_QV   = 65536;                      // B*CV*HWSZ        = 262144  (ch-first)
static const size_t OFF_MK   = 327680;                     // B*T*CK*PP        = 406272  (ch-first padded)
static const size_t OFF_MV   = 733952;                     // B*T*PP*CV        = 1625088 (ch-last padded)
static const size_t OFF_ATTN = 2359040;                    // (B*HH)*KK*WW     = 1382400 ([bh][k][w])
static const size_t OFF_PART = 3741440;                    // (B*HH)*T*2*64*32 = 786432
static const size_t ZERO_N   = 406272 + 1625088;           // mk+mv pad regions

__global__ __launch_bounds__(256) void k_zero(float* __restrict__ p, int n) {
    int i = blockIdx.x * 256 + threadIdx.x;
    if (i < n) p[i] = 0.f;
}

// Tiled GEMM proj. Grid = 8 jobs * 32 row-tiles.
__global__ __launch_bounds__(256) void k_proj(
    const float* __restrict__ x, const float* __restrict__ mem,
    const float* __restrict__ w_qk, const float* __restrict__ w_qv,
    const float* __restrict__ w_mk, const float* __restrict__ w_mv,
    float* __restrict__ ws)
{
    __shared__ float inT[KC][PIXT];      // 4 KB
    __shared__ float wT[NOUT][KC + 1];   // ~21 KB

    int jb   = blockIdx.x >> 5;          // 0..7
    int rowt = blockIdx.x & 31;          // h row
    int tid  = threadIdx.x;
    int tx   = tid & 7;                  // pixel quad
    int ty   = tid >> 3;                 // 5 outputs

    int b, t;
    const float *wk, *wv;
    bool isq;
    if (jb < 6) { b = jb / 3; t = jb % 3; wk = w_mk; wv = w_mv; isq = false; }
    else        { b = jb - 6; t = 0;      wk = w_qk; wv = w_qv; isq = true;  }

    const float* src = (t == 0)
        ? (x + ((size_t)b * C) * HWSZ)
        : (mem + ((size_t)(b * (T - 1) + (t - 1)) * C) * HWSZ);
    int hw0 = rowt * WW;

    float acc[5][4];
    #pragma unroll
    for (int j = 0; j < 5; j++)
        #pragma unroll
        for (int i = 0; i < 4; i++) acc[j][i] = 0.f;

    for (int c0 = 0; c0 < C; c0 += KC) {
        {
            int cc = tid >> 3;           // 0..31
            int p4 = (tid & 7) * 4;
            float4 v = *(const float4*)&src[(size_t)(c0 + cc) * HWSZ + hw0 + p4];
            inT[cc][p4 + 0] = v.x; inT[cc][p4 + 1] = v.y;
            inT[cc][p4 + 2] = v.z; inT[cc][p4 + 3] = v.w;
        }
        #pragma unroll
        for (int j = 0; j < 5; j++) {
            int f  = tid + j * 256;      // float4 index, 0..1279
            int o  = f >> 3;
            int c4 = (f & 7) * 4;
            const float* wr = (o < CK) ? (wk + (size_t)o * C) : (wv + (size_t)(o - CK) * C);
            float4 v = *(const float4*)&wr[c0 + c4];
            wT[o][c4 + 0] = v.x; wT[o][c4 + 1] = v.y;
            wT[o][c4 + 2] = v.z; wT[o][c4 + 3] = v.w;
        }
        __syncthreads();

        #pragma unroll 8
        for (int k = 0; k < KC; k++) {
            float4 iv = *(const float4*)&inT[k][tx * 4];
            #pragma unroll
            for (int j = 0; j < 5; j++) {
                float wv_ = wT[ty * 5 + j][k];
                acc[j][0] += wv_ * iv.x; acc[j][1] += wv_ * iv.y;
                acc[j][2] += wv_ * iv.z; acc[j][3] += wv_ * iv.w;
            }
        }
        __syncthreads();
    }

    int hq = rowt, yp = hq + PADSZ;
    float* mk = ws + OFF_MK;
    float* mv = ws + OFF_MV;
    #pragma unroll
    for (int j = 0; j < 5; j++) {
        int o = ty * 5 + j;
        #pragma unroll
        for (int i = 0; i < 4; i++) {
            int wq = tx * 4 + i;
            float v = acc[j][i];
            if (!isq) {
                int xp = wq + PADSZ;
                if (o < CK)
                    mk[(((size_t)(b * T + t) * CK + o) * PP) + yp * PADDED + xp] = v;
                else
                    mv[((size_t)(b * T + t) * PP + yp * PADDED + xp) * CV + (o - CK)] = v;
            } else {
                int hw = hq * WW + wq;
                if (o < CK) ws[OFF_QK + ((size_t)b * HWSZ + hw) * CK + o] = v;
                else        ws[OFF_QV + ((size_t)(b * CV + (o - CK))) * HWSZ + hw] = v;
            }
        }
    }
}

// Block per (b,h,t): q row in registers, mk row-segment staged in LDS per xx.
// attn layout out: [bh][k=675][w=32]
__global__ __launch_bounds__(256) void k_attn(
    const float* __restrict__ qk, const float* __restrict__ mk,
    float* __restrict__ attn)
{
    __shared__ float mkl[PADDED][36];    // 6.6 KB, [col][ch]

    int blk = blockIdx.x;
    int t   = blk % 3;
    int bh  = blk / 3;                   // b*HH + h
    int b   = bh >> 5, hq = bh & 31;
    int tid = threadIdx.x;
    int w   = tid & 31;
    int ty  = tid >> 5;                  // 0..7

    // q[w][0..31] into registers (reused across all 225 keys)
    float4 q[8];
    const float* qrow = qk + ((size_t)(b * HWSZ + hq * WW + w)) * CK;
    #pragma unroll
    for (int i = 0; i < 8; i++) q[i] = *(const float4*)&qrow[i * 4];

    const float* mkb = mk + ((size_t)(b * T + t) * CK) * PP;
    float* aout = attn + ((size_t)bh * KK + t * WSZ * WSZ) * WW;

    for (int xx = 0; xx < WSZ; xx++) {
        // stage mkl[col][c] (46 cols x 32 ch), coalesced 46-runs per channel
        for (int f = tid; f < PADDED * CK; f += 256) {
            int c = f / PADDED, col = f % PADDED;
            mkl[col][c] = mkb[(size_t)c * PP + (size_t)(hq + xx) * PADDED + col];
        }
        __syncthreads();

        #pragma unroll
        for (int yyp = 0; yyp < 2; yyp++) {
            int yy = yyp * 8 + ty;
            if (yy < WSZ) {
                float acc = 0.f;
                #pragma unroll
                for (int cq = 0; cq < 8; cq++) {
                    float4 m4 = *(const float4*)&mkl[w + yy][cq * 4];
                    acc += q[cq].x * m4.x + q[cq].y * m4.y
                         + q[cq].z * m4.z + q[cq].w * m4.w;
                }
                aout[(xx * WSZ + yy) * WW + w] = acc;
            }
        }
        __syncthreads();
    }
}

// Softmax over w (axis=2). One thread per (bh, k) — row of 32 contiguous floats.
__global__ __launch_bounds__(256) void k_softmax(float* __restrict__ attn)
{
    int idx = blockIdx.x * 256 + threadIdx.x;
    if (idx >= B * HH * KK) return;
    float* p = attn + (size_t)idx * WW;
    float4 v[8];
    float m = -1e30f;
    #pragma unroll
    for (int i = 0; i < 8; i++) {
        v[i] = *(const float4*)&p[i * 4];
        m = fmaxf(m, fmaxf(fmaxf(v[i].x, v[i].y), fmaxf(v[i].z, v[i].w)));
    }
    float s = 0.f;
    #pragma unroll
    for (int i = 0; i < 8; i++) {
        v[i].x = __expf(v[i].x - m); v[i].y = __expf(v[i].y - m);
        v[i].z = __expf(v[i].z - m); v[i].w = __expf(v[i].w - m);
        s += v[i].x + v[i].y + v[i].z + v[i].w;
    }
    float inv = 1.0f / s;
    #pragma unroll
    for (int i = 0; i < 8; i++) {
        v[i].x *= inv; v[i].y *= inv; v[i].z *= inv; v[i].w *= inv;
        *(float4*)&p[i * 4] = v[i];
    }
}

// Block per (bh, t, c-half): V row-segment in LDS, attn slice in LDS, t-partials out.
// part layout: [bh][t][chalf][c(64)][w(32)]
__global__ __launch_bounds__(256) void k_av(
    const float* __restrict__ attn, const float* __restrict__ mv,
    float* __restrict__ part)
{
    __shared__ float V[PADDED][68];      // 12.5 KB
    __shared__ float al[WSZ * WW];       // 1.9 KB

    int blk = blockIdx.x;
    int ch  = blk & 1;
    int t   = (blk >> 1) % 3;
    int bh  = blk / 6;
    int b   = bh >> 5, hq = bh & 31;
    int tid = threadIdx.x;
    int w   = tid & 31;
    int cg  = tid >> 5;                  // 0..7
    int c0  = ch * 64;

    const float* mvb = mv + (size_t)(b * T + t) * PP * CV;
    const float* ab  = attn + ((size_t)bh * KK + t * WSZ * WSZ) * WW;

    float acc[8];
    #pragma unroll
    for (int i = 0; i < 8; i++) acc[i] = 0.f;

    for (int xx = 0; xx < WSZ; xx++) {
        // stage V[col][c] : 46 cols x 64 ch (float4, coalesced)
        for (int f = tid; f < PADDED * 16; f += 256) {
            int col = f >> 4, cq = f & 15;
            float4 v4 = *(const float4*)&mvb[((size_t)(hq + xx) * PADDED + col) * CV + c0 + cq * 4];
            V[col][cq * 4 + 0] = v4.x; V[col][cq * 4 + 1] = v4.y;
            V[col][cq * 4 + 2] = v4.z; V[col][cq * 4 + 3] = v4.w;
        }
        // stage attn slice [yy][w] (coalesced)
        for (int f = tid; f < WSZ * WW; f += 256)
            al[f] = ab[(size_t)(xx * WSZ) * WW + f];
        __syncthreads();

        #pragma unroll
        for (int yy = 0; yy < WSZ; yy++) {
            float a = al[yy * WW + w];
            float4 v0 = *(const float4*)&V[w + yy][cg * 8];
            float4 v1 = *(const float4*)&V[w + yy][cg * 8 + 4];
            acc[0] += a * v0.x; acc[1] += a * v0.y;
            acc[2] += a * v0.z; acc[3] += a * v0.w;
            acc[4] += a * v1.x; acc[5] += a * v1.y;
            acc[6] += a * v1.z; acc[7] += a * v1.w;
        }
        __syncthreads();
    }

    float* pbase = part + ((size_t)(bh * T + t) * 2 + ch) * 2048;
    #pragma unroll
    for (int i = 0; i < 8; i++)
        pbase[(cg * 8 + i) * WW + w] = acc[i];
}

// Tiled GEMM out: feat=[qv;Σ_t part] @ w_smooth^T -> BN -> ReLU.
// Grid = B * 32 rowtiles * 2 output-halves. Block 256: 32 px x 128 outs.
__global__ __launch_bounds__(256) void k_out(
    const float* __restrict__ qv, const float* __restrict__ part,
    const float* __restrict__ wsm,
    const float* __restrict__ g, const float* __restrict__ bta,
    const float* __restrict__ mean, const float* __restrict__ var,
    float* __restrict__ out)
{
    __shared__ float inT[KC][PIXT];      // 4 KB, [ch][px]
    __shared__ float wTt[KC][132];       // 16.9 KB, [ch][o]

    int blk  = blockIdx.x;
    int oh   = blk & 1;                  // output half
    int rowt = (blk >> 1) & 31;
    int b    = blk >> 6;
    int tid  = threadIdx.x;
    int tx   = tid & 7;                  // pixel quad
    int ty   = tid >> 3;                 // 4 outputs
    int hw0  = rowt * WW;
    int obase = oh * 128;
    int bh   = b * HH + rowt;

    float acc[4][4];
    #pragma unroll
    for (int j = 0; j < 4; j++)
        #pragma unroll
        for (int i = 0; i < 4; i++) acc[j][i] = 0.f;

    for (int c0 = 0; c0 < C; c0 += KC) {
        // stage feat tile [ch][px]
        {
            int cc = tid >> 3;           // 0..31
            int p4 = (tid & 7) * 4;
            float4 v;
            if (c0 < CV) {
                v = *(const float4*)&qv[((size_t)(b * CV + c0 + cc)) * HWSZ + hw0 + p4];
            } else {
                int c0p   = c0 - CV;
                int chalf = c0p >> 6;
                int cloc  = (c0p & 63) + cc;
                const float* p0 = part + ((size_t)(bh * T + 0) * 2 + chalf) * 2048 + cloc * WW + p4;
                const float* p1 = part + ((size_t)(bh * T + 1) * 2 + chalf) * 2048 + cloc * WW + p4;
                const float* p2 = part + ((size_t)(bh * T + 2) * 2 + chalf) * 2048 + cloc * WW + p4;
                float4 a = *(const float4*)p0, bb = *(const float4*)p1, cc4 = *(const float4*)p2;
                v.x = a.x + bb.x + cc4.x; v.y = a.y + bb.y + cc4.y;
                v.z = a.z + bb.z + cc4.z; v.w = a.w + bb.w + cc4.w;
            }
            inT[cc][p4 + 0] = v.x; inT[cc][p4 + 1] = v.y;
            inT[cc][p4 + 2] = v.z; inT[cc][p4 + 3] = v.w;
        }
        // stage weight tile transposed [ch][o]
        #pragma unroll
        for (int j = 0; j < 4; j++) {
            int f  = tid + j * 256;      // float4 idx 0..1023
            int o  = f >> 3;             // 0..127
            int c4 = (f & 7) * 4;
            float4 v = *(const float4*)&wsm[(size_t)(obase + o) * C + c0 + c4];
            wTt[c4 + 0][o] = v.x; wTt[c4 + 1][o] = v.y;
            wTt[c4 + 2][o] = v.z; wTt[c4 + 3][o] = v.w;
        }
        __syncthreads();

        #pragma unroll 8
        for (int k = 0; k < KC; k++) {
            float4 iv  = *(const float4*)&inT[k][tx * 4];
            float4 wv4 = *(const float4*)&wTt[k][ty * 4];
            acc[0][0] += wv4.x * iv.x; acc[0][1] += wv4.x * iv.y;
            acc[0][2] += wv4.x * iv.z; acc[0][3] += wv4.x * iv.w;
            acc[1][0] += wv4.y * iv.x; acc[1][1] += wv4.y * iv.y;
            acc[1][2] += wv4.y * iv.z; acc[1][3] += wv4.y * iv.w;
            acc[2][0] += wv4.z * iv.x; acc[2][1] += wv4.z * iv.y;
            acc[2][2] += wv4.z * iv.z; acc[2][3] += wv4.z * iv.w;
            acc[3][0] += wv4.w * iv.x; acc[3][1] += wv4.w * iv.y;
            acc[3][2] += wv4.w * iv.z; acc[3][3] += wv4.w * iv.w;
        }
        __syncthreads();
    }

    #pragma unroll
    for (int j = 0; j < 4; j++) {
        int o = obase + ty * 4 + j;
        float inv = g[o] * rsqrtf(var[o] + 1e-5f);
        float sh  = bta[o] - mean[o] * inv;
        float4 r;
        r.x = fmaxf(acc[j][0] * inv + sh, 0.f);
        r.y = fmaxf(acc[j][1] * inv + sh, 0.f);
        r.z = fmaxf(acc[j][2] * inv + sh, 0.f);
        r.w = fmaxf(acc[j][3] * inv + sh, 0.f);
        *(float4*)&out[((size_t)(b * C + o)) * HWSZ + hw0 + tx * 4] = r;
    }
}

extern "C" void kernel_launch(void* const* d_in, const int* in_sizes, int n_in,
                              void* d_out, int out_size, void* d_ws, size_t ws_size,
                              hipStream_t stream) {
    const float* x    = (const float*)d_in[0];
    const float* mem  = (const float*)d_in[1];
    const float* w_qk = (const float*)d_in[2];
    const float* w_qv = (const float*)d_in[3];
    const float* w_mk = (const float*)d_in[4];
    const float* w_mv = (const float*)d_in[5];
    const float* wsm  = (const float*)d_in[6];
    const float* g    = (const float*)d_in[7];
    const float* bta  = (const float*)d_in[8];
    const float* mean = (const float*)d_in[9];
    const float* var  = (const float*)d_in[10];
    float* out = (float*)d_out;
    float* ws  = (float*)d_ws;

    {
        int n = (int)ZERO_N;
        k_zero<<<(n + 255) / 256, 256, 0, stream>>>(ws + OFF_MK, n);
    }
    k_proj<<<8 * 32, 256, 0, stream>>>(x, mem, w_qk, w_qv, w_mk, w_mv, ws);
    k_attn<<<B * HH * T, 256, 0, stream>>>(ws + OFF_QK, ws + OFF_MK, ws + OFF_ATTN);
    {
        int n = B * HH * KK;
        k_softmax<<<(n + 255) / 256, 256, 0, stream>>>(ws + OFF_ATTN);
    }
    k_av<<<B * HH * T * 2, 256, 0, stream>>>(ws + OFF_ATTN, ws + OFF_MV, ws + OFF_PART);
    k_out<<<B * 32 * 2, 256, 0, stream>>>(ws + OFF_QV, ws + OFF_PART, wsm, g, bta, mean, var, out);
}

// Round 5
// 86.592 us; speedup vs baseline: 1.5753x; 1.5753x over previous
//
#include <hip/hip_runtime.h>
#include <math.h>

#define HWSZ 1024
#define HH 32
#define WW 32
#define C 256
#define CK 32
#define CV 128
#define T 3
#define WSZ 15
#define PADSZ 7
#define PADDED 46
#define PP (PADDED*PADDED)   // 2116
#define KK (T*WSZ*WSZ)       // 675
#define B 2
#define NOUT 160             // CK + CV
#define KC 32                // k-chunk
#define PIXT 32              // pixel tile (one image row)

// workspace layout (floats)
static const size_t OFF_QK   = 0;                          // B*HWSZ*CK        = 65536   ([pix][32])
static const size_t OFF_QV   = 65536;                      // B*CV*HWSZ        = 262144  (ch-first)
static const size_t OFF_MK   = 327680;                     // B*T*CK*PP        = 406272  (ch-first padded)
static const size_t OFF_MV   = 733952;                     // B*T*PP*CV        = 1625088 (ch-last padded)
static const size_t OFF_ATTN = 2359040;                    // (B*HH)*KK*WW     = 1382400 ([bh][k][w])
static const size_t OFF_PART = 3741440;                    // (B*HH)*9*128*32  = 2359296
static const size_t ZERO_N   = 406272 + 1625088;           // mk+mv pad regions

__global__ __launch_bounds__(256) void k_zero(float* __restrict__ p, int n) {
    int i = blockIdx.x * 256 + threadIdx.x;
    if (i < n) p[i] = 0.f;
}

// Tiled GEMM proj. Grid = 8 jobs * 32 row-tiles.
__global__ __launch_bounds__(256) void k_proj(
    const float* __restrict__ x, const float* __restrict__ mem,
    const float* __restrict__ w_qk, const float* __restrict__ w_qv,
    const float* __restrict__ w_mk, const float* __restrict__ w_mv,
    float* __restrict__ ws)
{
    __shared__ float inT[KC][PIXT];      // 4 KB
    __shared__ float wT[NOUT][KC + 1];   // ~21 KB

    int jb   = blockIdx.x >> 5;          // 0..7
    int rowt = blockIdx.x & 31;          // h row
    int tid  = threadIdx.x;
    int tx   = tid & 7;                  // pixel quad
    int ty   = tid >> 3;                 // 5 outputs

    int b, t;
    const float *wk, *wv;
    bool isq;
    if (jb < 6) { b = jb / 3; t = jb % 3; wk = w_mk; wv = w_mv; isq = false; }
    else        { b = jb - 6; t = 0;      wk = w_qk; wv = w_qv; isq = true;  }

    const float* src = (t == 0)
        ? (x + ((size_t)b * C) * HWSZ)
        : (mem + ((size_t)(b * (T - 1) + (t - 1)) * C) * HWSZ);
    int hw0 = rowt * WW;

    float acc[5][4];
    #pragma unroll
    for (int j = 0; j < 5; j++)
        #pragma unroll
        for (int i = 0; i < 4; i++) acc[j][i] = 0.f;

    for (int c0 = 0; c0 < C; c0 += KC) {
        {
            int cc = tid >> 3;           // 0..31
            int p4 = (tid & 7) * 4;
            float4 v = *(const float4*)&src[(size_t)(c0 + cc) * HWSZ + hw0 + p4];
            inT[cc][p4 + 0] = v.x; inT[cc][p4 + 1] = v.y;
            inT[cc][p4 + 2] = v.z; inT[cc][p4 + 3] = v.w;
        }
        #pragma unroll
        for (int j = 0; j < 5; j++) {
            int f  = tid + j * 256;      // float4 index, 0..1279
            int o  = f >> 3;
            int c4 = (f & 7) * 4;
            const float* wr = (o < CK) ? (wk + (size_t)o * C) : (wv + (size_t)(o - CK) * C);
            float4 v = *(const float4*)&wr[c0 + c4];
            wT[o][c4 + 0] = v.x; wT[o][c4 + 1] = v.y;
            wT[o][c4 + 2] = v.z; wT[o][c4 + 3] = v.w;
        }
        __syncthreads();

        #pragma unroll 8
        for (int k = 0; k < KC; k++) {
            float4 iv = *(const float4*)&inT[k][tx * 4];
            #pragma unroll
            for (int j = 0; j < 5; j++) {
                float wv_ = wT[ty * 5 + j][k];
                acc[j][0] += wv_ * iv.x; acc[j][1] += wv_ * iv.y;
                acc[j][2] += wv_ * iv.z; acc[j][3] += wv_ * iv.w;
            }
        }
        __syncthreads();
    }

    int hq = rowt, yp = hq + PADSZ;
    float* mk = ws + OFF_MK;
    float* mv = ws + OFF_MV;
    #pragma unroll
    for (int j = 0; j < 5; j++) {
        int o = ty * 5 + j;
        #pragma unroll
        for (int i = 0; i < 4; i++) {
            int wq = tx * 4 + i;
            float v = acc[j][i];
            if (!isq) {
                int xp = wq + PADSZ;
                if (o < CK)
                    mk[(((size_t)(b * T + t) * CK + o) * PP) + yp * PADDED + xp] = v;
                else
                    mv[((size_t)(b * T + t) * PP + yp * PADDED + xp) * CV + (o - CK)] = v;
            } else {
                int hw = hq * WW + wq;
                if (o < CK) ws[OFF_QK + ((size_t)b * HWSZ + hw) * CK + o] = v;
                else        ws[OFF_QV + ((size_t)(b * CV + (o - CK))) * HWSZ + hw] = v;
            }
        }
    }
}

// Fused attn + softmax. Block per (b,h,t,xx) = 2880 blocks, one barrier, no loop.
// Softmax over w (axis=2) is per-key and all 32 w live in this block -> shfl reduce.
// attn out layout: [bh][k=675][w=32]
__global__ __launch_bounds__(256) void k_attn_sm(
    const float* __restrict__ qk, const float* __restrict__ mk,
    float* __restrict__ attn)
{
    __shared__ float mkl[PADDED][36];    // 6.6 KB [col][ch]
    __shared__ float ql[WW][36];         // 4.6 KB [w][ch]

    int blk = blockIdx.x;
    int xx  = blk % WSZ;
    int rem = blk / WSZ;
    int t   = rem % T;
    int bh  = rem / T;                   // b*HH + h
    int b   = bh >> 5, hq = bh & 31;
    int tid = threadIdx.x;
    int w   = tid & 31;
    int ty  = tid >> 5;                  // 0..7

    const float* mkb = mk + ((size_t)(b * T + t) * CK) * PP;

    // stage mk row-segment [46 cols][32 ch]
    for (int f = tid; f < PADDED * CK; f += 256) {
        int c = f / PADDED, col = f - c * PADDED;
        mkl[col][c] = mkb[(size_t)c * PP + (size_t)(hq + xx) * PADDED + col];
    }
    // stage q rows [32 w][32 ch] (coalesced)
    for (int f = tid; f < WW * CK; f += 256) {
        int w2 = f >> 5, c = f & 31;
        ql[w2][c] = qk[((size_t)(b * HWSZ + hq * WW + w2)) * CK + c];
    }
    __syncthreads();

    // q into registers (reused for 2 yy)
    float4 q[8];
    #pragma unroll
    for (int i = 0; i < 8; i++) q[i] = *(const float4*)&ql[w][i * 4];

    int yy0 = ty;
    int yy1 = ty + 8;
    int row1 = (yy1 < WSZ) ? yy1 : 14;   // clamp to keep LDS reads in-bounds

    float s0 = 0.f, s1 = 0.f;
    #pragma unroll
    for (int cq = 0; cq < 8; cq++) {
        float4 m0 = *(const float4*)&mkl[w + yy0][cq * 4];
        float4 m1 = *(const float4*)&mkl[w + row1][cq * 4];
        s0 += q[cq].x * m0.x + q[cq].y * m0.y + q[cq].z * m0.z + q[cq].w * m0.w;
        s1 += q[cq].x * m1.x + q[cq].y * m1.y + q[cq].z * m1.z + q[cq].w * m1.w;
    }

    // softmax over the 32 w lanes (per key)
    float m0 = s0, m1 = s1;
    #pragma unroll
    for (int d = 1; d < 32; d <<= 1) {
        m0 = fmaxf(m0, __shfl_xor(m0, d, 32));
        m1 = fmaxf(m1, __shfl_xor(m1, d, 32));
    }
    float e0 = __expf(s0 - m0), e1 = __expf(s1 - m1);
    float t0 = e0, t1 = e1;
    #pragma unroll
    for (int d = 1; d < 32; d <<= 1) {
        t0 += __shfl_xor(t0, d, 32);
        t1 += __shfl_xor(t1, d, 32);
    }
    float a0 = e0 / t0, a1 = e1 / t1;

    float* aout = attn + ((size_t)bh * KK + t * WSZ * WSZ + xx * WSZ) * WW;
    aout[yy0 * WW + w] = a0;
    if (yy1 < WSZ) aout[yy1 * WW + w] = a1;
}

// AV partials. Block per (bh, t, xg) = 576 blocks; xg covers 5 xx rows.
// Thread tile: 4 ch x 4 w with an 18-col float4 register window over V.
// part layout: [bh][tg=t*3+xg][c(128)][w(32)]
__global__ __launch_bounds__(256) void k_av(
    const float* __restrict__ attn, const float* __restrict__ mv,
    float* __restrict__ part)
{
    __shared__ float V[PADDED][132];     // 24.3 KB
    __shared__ float al[WSZ * WW];       // 1.9 KB

    int blk = blockIdx.x;
    int xg  = blk % 3;
    int rem = blk / 3;
    int t   = rem % T;
    int bh  = rem / T;
    int b   = bh >> 5, hq = bh & 31;
    int tid = threadIdx.x;
    int wq  = tid & 7;                   // w quad
    int cg  = tid >> 3;                  // 0..31 channel quad
    int w0  = wq * 4;
    int c0  = cg * 4;

    const float* mvb = mv + (size_t)(b * T + t) * PP * CV;
    const float* ab  = attn + ((size_t)bh * KK + t * WSZ * WSZ) * WW;

    float acc[4][4];
    #pragma unroll
    for (int ci = 0; ci < 4; ci++)
        #pragma unroll
        for (int wi = 0; wi < 4; wi++) acc[ci][wi] = 0.f;

    for (int xi = 0; xi < 5; xi++) {
        int xx = xg * 5 + xi;
        // stage V[col][c]: 46 cols x 128 ch, coalesced float4
        for (int f = tid; f < PADDED * 32; f += 256) {
            int col = f >> 5, cq = f & 31;
            float4 v4 = *(const float4*)&mvb[((size_t)(hq + xx) * PADDED + col) * CV + cq * 4];
            V[col][cq * 4 + 0] = v4.x; V[col][cq * 4 + 1] = v4.y;
            V[col][cq * 4 + 2] = v4.z; V[col][cq * 4 + 3] = v4.w;
        }
        // stage attn slice [15 yy][32 w]
        for (int f = tid; f < WSZ * WW; f += 256)
            al[f] = ab[(size_t)(xx * WSZ) * WW + f];
        __syncthreads();

        // register window: 18 cols of this thread's 4 channels
        float4 vw[18];
        #pragma unroll
        for (int i = 0; i < 18; i++)
            vw[i] = *(const float4*)&V[w0 + i][c0];

        #pragma unroll
        for (int yy = 0; yy < WSZ; yy++) {
            float4 a4 = *(const float4*)&al[yy * WW + w0];
            #pragma unroll
            for (int wi = 0; wi < 4; wi++) {
                float av = (wi == 0) ? a4.x : (wi == 1) ? a4.y : (wi == 2) ? a4.z : a4.w;
                float4 vv = vw[yy + wi];
                acc[0][wi] += av * vv.x;
                acc[1][wi] += av * vv.y;
                acc[2][wi] += av * vv.z;
                acc[3][wi] += av * vv.w;
            }
        }
        __syncthreads();
    }

    float* pbase = part + ((size_t)(bh * 9 + (t * 3 + xg)) * CV) * WW;
    #pragma unroll
    for (int ci = 0; ci < 4; ci++) {
        float4 r; r.x = acc[ci][0]; r.y = acc[ci][1]; r.z = acc[ci][2]; r.w = acc[ci][3];
        *(float4*)&pbase[(c0 + ci) * WW + w0] = r;
    }
}

// Tiled GEMM out: feat=[qv; sum_9 part] @ w_smooth^T -> BN -> ReLU.
// Grid = B * 32 rowtiles * 2 output-halves. Block 256: 32 px x 128 outs.
__global__ __launch_bounds__(256) void k_out(
    const float* __restrict__ qv, const float* __restrict__ part,
    const float* __restrict__ wsm,
    const float* __restrict__ g, const float* __restrict__ bta,
    const float* __restrict__ mean, const float* __restrict__ var,
    float* __restrict__ out)
{
    __shared__ float inT[KC][PIXT];      // 4 KB, [ch][px]
    __shared__ float wTt[KC][132];       // 16.9 KB, [ch][o]

    int blk  = blockIdx.x;
    int oh   = blk & 1;                  // output half
    int rowt = (blk >> 1) & 31;
    int b    = blk >> 6;
    int tid  = threadIdx.x;
    int tx   = tid & 7;                  // pixel quad
    int ty   = tid >> 3;                 // 4 outputs
    int hw0  = rowt * WW;
    int obase = oh * 128;
    int bh   = b * HH + rowt;

    float acc[4][4];
    #pragma unroll
    for (int j = 0; j < 4; j++)
        #pragma unroll
        for (int i = 0; i < 4; i++) acc[j][i] = 0.f;

    for (int c0 = 0; c0 < C; c0 += KC) {
        // stage feat tile [ch][px]
        {
            int cc = tid >> 3;           // 0..31
            int p4 = (tid & 7) * 4;
            float4 v;
            if (c0 < CV) {
                v = *(const float4*)&qv[((size_t)(b * CV + c0 + cc)) * HWSZ + hw0 + p4];
            } else {
                int cloc = (c0 - CV) + cc;
                const float* pb = part + ((size_t)bh * 9) * CV * WW + cloc * WW + p4;
                float4 s = *(const float4*)pb;
                #pragma unroll
                for (int tg = 1; tg < 9; tg++) {
                    float4 a = *(const float4*)&pb[(size_t)tg * CV * WW];
                    s.x += a.x; s.y += a.y; s.z += a.z; s.w += a.w;
                }
                v = s;
            }
            inT[cc][p4 + 0] = v.x; inT[cc][p4 + 1] = v.y;
            inT[cc][p4 + 2] = v.z; inT[cc][p4 + 3] = v.w;
        }
        // stage weight tile transposed [ch][o]
        #pragma unroll
        for (int j = 0; j < 4; j++) {
            int f  = tid + j * 256;      // float4 idx 0..1023
            int o  = f >> 3;             // 0..127
            int c4 = (f & 7) * 4;
            float4 v = *(const float4*)&wsm[(size_t)(obase + o) * C + c0 + c4];
            wTt[c4 + 0][o] = v.x; wTt[c4 + 1][o] = v.y;
            wTt[c4 + 2][o] = v.z; wTt[c4 + 3][o] = v.w;
        }
        __syncthreads();

        #pragma unroll 8
        for (int k = 0; k < KC; k++) {
            float4 iv  = *(const float4*)&inT[k][tx * 4];
            float4 wv4 = *(const float4*)&wTt[k][ty * 4];
            acc[0][0] += wv4.x * iv.x; acc[0][1] += wv4.x * iv.y;
            acc[0][2] += wv4.x * iv.z; acc[0][3] += wv4.x * iv.w;
            acc[1][0] += wv4.y * iv.x; acc[1][1] += wv4.y * iv.y;
            acc[1][2] += wv4.y * iv.z; acc[1][3] += wv4.y * iv.w;
            acc[2][0] += wv4.z * iv.x; acc[2][1] += wv4.z * iv.y;
            acc[2][2] += wv4.z * iv.z; acc[2][3] += wv4.z * iv.w;
            acc[3][0] += wv4.w * iv.x; acc[3][1] += wv4.w * iv.y;
            acc[3][2] += wv4.w * iv.z; acc[3][3] += wv4.w * iv.w;
        }
        __syncthreads();
    }

    #pragma unroll
    for (int j = 0; j < 4; j++) {
        int o = obase + ty * 4 + j;
        float inv = g[o] * rsqrtf(var[o] + 1e-5f);
        float sh  = bta[o] - mean[o] * inv;
        float4 r;
        r.x = fmaxf(acc[j][0] * inv + sh, 0.f);
        r.y = fmaxf(acc[j][1] * inv + sh, 0.f);
        r.z = fmaxf(acc[j][2] * inv + sh, 0.f);
        r.w = fmaxf(acc[j][3] * inv + sh, 0.f);
        *(float4*)&out[((size_t)(b * C + o)) * HWSZ + hw0 + tx * 4] = r;
    }
}

extern "C" void kernel_launch(void* const* d_in, const int* in_sizes, int n_in,
                              void* d_out, int out_size, void* d_ws, size_t ws_size,
                              hipStream_t stream) {
    const float* x    = (const float*)d_in[0];
    const float* mem  = (const float*)d_in[1];
    const float* w_qk = (const float*)d_in[2];
    const float* w_qv = (const float*)d_in[3];
    const float* w_mk = (const float*)d_in[4];
    const float* w_mv = (const float*)d_in[5];
    const float* wsm  = (const float*)d_in[6];
    const float* g    = (const float*)d_in[7];
    const float* bta  = (const float*)d_in[8];
    const float* mean = (const float*)d_in[9];
    const float* var  = (const float*)d_in[10];
    float* out = (float*)d_out;
    float* ws  = (float*)d_ws;

    {
        int n = (int)ZERO_N;
        k_zero<<<(n + 255) / 256, 256, 0, stream>>>(ws + OFF_MK, n);
    }
    k_proj<<<8 * 32, 256, 0, stream>>>(x, mem, w_qk, w_qv, w_mk, w_mv, ws);
    k_attn_sm<<<B * HH * T * WSZ, 256, 0, stream>>>(ws + OFF_QK, ws + OFF_MK, ws + OFF_ATTN);
    k_av<<<B * HH * T * 3, 256, 0, stream>>>(ws + OFF_ATTN, ws + OFF_MV, ws + OFF_PART);
    k_out<<<B * 32 * 2, 256, 0, stream>>>(ws + OFF_QV, ws + OFF_PART, wsm, g, bta, mean, var, out);
}